// Round 5
// baseline (700.922 us; speedup 1.0000x reference)
//
#include <hip/hip_runtime.h>
#include <hip/hip_bf16.h>

#define EDGES 160000
#define NNODES 10000

typedef __attribute__((ext_vector_type(8))) short short8;
typedef __attribute__((ext_vector_type(4))) float f32x4;

__device__ __forceinline__ float fsigmoid(float x) {
    return 1.0f / (1.0f + __expf(-x));
}

union F8 { uint32_t u[4]; short8 s8; };

// packed bf16 pair: low16 = bf16(e0), high16 = bf16(e1), RNE
__device__ __forceinline__ uint32_t pk2(float e0, float e1) {
    uint32_t r;
    asm("v_cvt_pk_bf16_f32 %0, %1, %2" : "=v"(r) : "v"(e0), "v"(e1));
    return r;
}

// Dekker-style split of 8 fp32 into bf16 hi + bf16 lo fragments
__device__ __forceinline__ void split8(const float* x, F8& ah, F8& al) {
    #pragma unroll
    for (int r = 0; r < 4; ++r) {
        const float x0 = x[2*r], x1 = x[2*r+1];
        const uint32_t h = pk2(x0, x1);
        ah.u[r] = h;
        const float f0 = __uint_as_float(h << 16);
        const float f1 = __uint_as_float(h & 0xffff0000u);
        al.u[r] = pk2(x0 - f0, x1 - f1);
    }
}

__device__ __forceinline__ f32x4 mm(const F8& a, const F8& b, f32x4 c) {
    return __builtin_amdgcn_mfma_f32_16x16x32_bf16(a.s8, b.s8, c, 0, 0, 0);
}

__device__ __forceinline__ void ld_b(const uint4* p, int idx, F8& d) {
    const uint4 v = p[idx];
    d.u[0] = v.x; d.u[1] = v.y; d.u[2] = v.z; d.u[3] = v.w;
}

// ---------------------------------------------------------------------------
// MLP evaluation: edge e -> wgt[64]
// ---------------------------------------------------------------------------
__device__ __forceinline__ void mlp_eval(int e,
              const float* __restrict__ edge_fea,
              const float* __restrict__ w1, const float* __restrict__ b1,
              const float* __restrict__ w2, const float* __restrict__ b2,
              const float* __restrict__ w3, const float* __restrict__ b3,
              float* wgt)
{
    float s[32];
    const float4* f4 = reinterpret_cast<const float4*>(edge_fea + (size_t)e * 80);
    #pragma unroll
    for (int q = 0; q < 8; ++q) {
        float4 v = f4[q];
        s[4*q+0] = v.x; s[4*q+1] = v.y; s[4*q+2] = v.z; s[4*q+3] = v.w;
    }
    float h[64];
    #pragma unroll
    for (int k = 0; k < 64; ++k) h[k] = b1[k];
    #pragma unroll
    for (int i = 0; i < 32; ++i) {
        const float si = s[i];
        #pragma unroll
        for (int k = 0; k < 64; ++k) h[k] = fmaf(si, w1[i*64+k], h[k]);
    }
    #pragma unroll
    for (int k = 0; k < 64; ++k) h[k] = h[k] * fsigmoid(h[k]);
    float h2[64];
    #pragma unroll
    for (int k = 0; k < 64; ++k) h2[k] = b2[k];
    #pragma unroll
    for (int i = 0; i < 64; ++i) {
        const float si = h[i];
        #pragma unroll
        for (int k = 0; k < 64; ++k) h2[k] = fmaf(si, w2[i*64+k], h2[k]);
    }
    #pragma unroll
    for (int k = 0; k < 64; ++k) h2[k] = h2[k] * fsigmoid(h2[k]);
    #pragma unroll
    for (int k = 0; k < 64; ++k) wgt[k] = b3[k];
    #pragma unroll
    for (int i = 0; i < 64; ++i) {
        const float si = h2[i];
        #pragma unroll
        for (int k = 0; k < 64; ++k) wgt[k] = fmaf(si, w3[i*64+k], wgt[k]);
    }
}

// ---------------------------------------------------------------------------
// Stage A: CSR build + MLP->slot store + gather reduce
// ---------------------------------------------------------------------------
extern "C" __global__ void __launch_bounds__(256)
k_hist(const int* __restrict__ idx_i, int* __restrict__ counts)
{
    const int e = blockIdx.x * 256 + threadIdx.x;
    if (e < EDGES) atomicAdd(&counts[idx_i[e]], 1);
}

extern "C" __global__ void __launch_bounds__(256)
k_scan(const int* __restrict__ counts, int* __restrict__ offsets,
       int* __restrict__ cursor)
{
    __shared__ int sc[2][256];
    const int t = threadIdx.x;
    const int base = t * 40;
    int loc[40];
    int s = 0;
    #pragma unroll
    for (int k = 0; k < 40; ++k) {
        const int idx = base + k;
        const int c = (idx < NNODES) ? counts[idx] : 0;
        loc[k] = c; s += c;
    }
    sc[0][t] = s;
    __syncthreads();
    int src = 0;
    for (int off = 1; off < 256; off <<= 1) {
        int v = sc[src][t];
        if (t >= off) v += sc[src][t - off];
        sc[src ^ 1][t] = v;
        __syncthreads();
        src ^= 1;
    }
    int run = sc[src][t] - s;          // exclusive prefix
    #pragma unroll
    for (int k = 0; k < 40; ++k) {
        const int idx = base + k;
        if (idx < NNODES) {
            offsets[idx] = run;
            cursor[idx]  = run;
            run += loc[k];
        }
    }
    if (t == 255) offsets[NNODES] = EDGES;
}

// __launch_bounds__(256, 2): grid is only 625 blocks (~2.4 waves/SIMD), so
// occupancy can never exceed ~3 waves/SIMD anyway — raise the VGPR cap to 256
// so the 128+-live MLP activation arrays stay in registers (VGPR=100 spilled).
extern "C" __global__ void __launch_bounds__(256, 2)
k_mlp_store(const float* __restrict__ edge_sh,
            const float* __restrict__ edge_fea,
            const int* __restrict__ idx_i,
            const float* __restrict__ w1, const float* __restrict__ b1,
            const float* __restrict__ w2, const float* __restrict__ b2,
            const float* __restrict__ w3, const float* __restrict__ b3,
            int* __restrict__ cursor,
            float* __restrict__ wgtbuf, float* __restrict__ shbuf)
{
    const int e = blockIdx.x * 256 + threadIdx.x;
    float wgt[64];
    mlp_eval(e, edge_fea, w1, b1, w2, b2, w3, b3, wgt);

    const int ni = idx_i[e];
    const int slot = atomicAdd(&cursor[ni], 1);
    float4* wp = reinterpret_cast<float4*>(wgtbuf + (size_t)slot * 64);
    #pragma unroll
    for (int q = 0; q < 16; ++q)
        wp[q] = make_float4(wgt[4*q], wgt[4*q+1], wgt[4*q+2], wgt[4*q+3]);
    *reinterpret_cast<float4*>(shbuf + (size_t)slot * 4) =
        *reinterpret_cast<const float4*>(edge_sh + (size_t)e * 4);
}

extern "C" __global__ void __launch_bounds__(256)
k_reduce(const int* __restrict__ offsets,
         const float* __restrict__ wgtbuf, const float* __restrict__ shbuf,
         float* __restrict__ nsI, float* __restrict__ nsJ,
         float* __restrict__ nvI, float* __restrict__ nvJ)
{
    const int tid = threadIdx.x;
    const int n = blockIdx.x * 2 + (tid >> 7);
    const int o = tid & 127;

    int widx, shc;
    float* dst;
    if (o < 16)      { widx = o;            shc = 0;     dst = &nsI[n*16 + o]; }
    else if (o < 64) { const int r = o - 16; const int m = r / 3, c = r - 3*m;
                       widx = 16 + m;       shc = 1 + c; dst = &nvI[(n*16 + m)*3 + c]; }
    else if (o < 80) { const int r = o - 64;
                       widx = 32 + r;       shc = 0;     dst = &nsJ[n*16 + r]; }
    else             { const int r = o - 80; const int m = r / 3, c = r - 3*m;
                       widx = 48 + m;       shc = 1 + c; dst = &nvJ[(n*16 + m)*3 + c]; }

    const int s0 = offsets[n], s1 = offsets[n + 1];
    float acc = 0.0f;
    for (int s = s0; s < s1; ++s)
        acc = fmaf(wgtbuf[(size_t)s*64 + widx], shbuf[(size_t)s*4 + shc], acc);
    *dst = acc;
}

// ---------------------------------------------------------------------------
// k_pack: weights -> MFMA B-fragment layout, bf16 hi/lo split, scales folded.
// Fragment index: segbase + ((kc*tiles + tile)*2 + h)*64 + lane  (uint4 each)
//   lane l: o = tile*16 + (l&15), k = kc*32 + (l>>4)*8 + [0..8)
//   uint4 word r = pk(bf16(k=2r), bf16(k=2r+1))
// segs: ss[K=1024,t=3]@0  vv[512,3]@12288  sv[512,1]@18432  vs[1024,1]@20480
// ---------------------------------------------------------------------------
extern "C" __global__ void __launch_bounds__(256)
k_pack(const float* __restrict__ w_ss, const float* __restrict__ w_vv,
       const float* __restrict__ w_sv, const float* __restrict__ w_vs,
       uint4* __restrict__ pk)
{
    const int t = blockIdx.x * 256 + threadIdx.x;     // [0, 24576)
    const float INV2  = 0.70710678118654752f;
    const float RS512 = 22.627416997969522f;
    const float C3    = 0.57735026918962576f;

    const float* W; int K; float scale; int local; int tiles;
    if (t < 12288)      { W = w_ss; K = 1024; scale = INV2/32.0f;     local = t;         tiles = 3; }
    else if (t < 18432) { W = w_vv; K = 512;  scale = INV2*C3/RS512;  local = t - 12288; tiles = 3; }
    else if (t < 20480) { W = w_sv; K = 512;  scale = INV2/RS512;     local = t - 18432; tiles = 1; }
    else                { W = w_vs; K = 1024; scale = INV2/32.0f;     local = t - 20480; tiles = 1; }

    const int l    = local & 63;
    const int h    = (local >> 6) & 1;
    const int rest = local >> 7;               // kc*tiles + tile
    const int tile = rest % tiles;
    const int kc   = rest / tiles;
    const int o    = tile*16 + (l & 15);
    const int kb   = kc*32 + (l >> 4)*8;

    const float4* src = reinterpret_cast<const float4*>(W + (size_t)o * K + kb);
    const float4 a = src[0], b = src[1];
    const float v[8] = {a.x, a.y, a.z, a.w, b.x, b.y, b.z, b.w};

    uint32_t out[4];
    #pragma unroll
    for (int r = 0; r < 4; ++r) {
        const float x0 = v[2*r] * scale, x1 = v[2*r+1] * scale;
        const uint32_t hi = pk2(x0, x1);
        if (h == 0) out[r] = hi;
        else {
            const float f0 = __uint_as_float(hi << 16);
            const float f1 = __uint_as_float(hi & 0xffff0000u);
            out[r] = pk2(x0 - f0, x1 - f1);
        }
    }
    pk[t] = make_uint4(out[0], out[1], out[2], out[3]);
}

// ---------------------------------------------------------------------------
// Stage B: MFMA contraction. 64 edges/block, 8 waves.
//   waves 0..3 (edge-quarter q): o_s — G1 (S1 x S2, K=1024) + G2 (sum_c V1c x V2c,
//     K=512), 3 N-tiles of 16 outputs, acc[3] f32x4.
//   waves 4..7 (edge-quarter q): o_v — G3 (S1 x V2c, K=512) + G4 (V1c x S2,
//     K=1024), 1 N-tile, 3 components c, acc[3] f32x4. B shared across c.
// A split into bf16 hi/lo, W pre-split -> 3 MFMA per (chunk, tile): hh, lh, hl.
// ---------------------------------------------------------------------------
extern "C" __global__ void __launch_bounds__(512)
k_contract(const float* __restrict__ edge_fea,
           const int* __restrict__ idx_i, const int* __restrict__ idx_j,
           const float* __restrict__ nsI, const float* __restrict__ nsJ,
           const float* __restrict__ nvI, const float* __restrict__ nvJ,
           const uint4* __restrict__ pk,
           float* __restrict__ out)
{
    __shared__ float lds[13568];              // 54272 B -> 3 blocks/CU by LDS
    float* sS1T = lds;                        // [32][64]
    float* sS2  = lds + 2048;                 // [64][33] (+1 pad)
    float* sV1T = lds + 4160;                 // [3][32][64]
    float* sV2  = lds + 10304;                // [3][64][17] (+1 pad)
    float* sOs  = lds;                        // [48][65] reuse (epilogue)
    float* sOv  = lds + 4160;                 // [48][65] reuse (epilogue)

    const int tid = threadIdx.x;
    const int e0  = blockIdx.x * 64;

    // ---- gather S2 / V2 from edge_fea ----
    for (int t = tid; t < 64*20; t += 512) {
        const int ge = t & 63, qd = t >> 6;
        const float4 v = *reinterpret_cast<const float4*>(
            edge_fea + (size_t)(e0 + ge) * 80 + qd * 4);
        const float vv4[4] = {v.x, v.y, v.z, v.w};
        #pragma unroll
        for (int u = 0; u < 4; ++u) {
            const int f = qd*4 + u;
            if (f < 32) sS2[ge*33 + f] = vv4[u];
            else {
                const int r = f - 32;               // r = j*3 + c
                sV2[(r % 3)*1088 + ge*17 + r/3] = vv4[u];
            }
        }
    }
    // ---- gather S1 (transposed) ----
    for (int t = tid; t < 2048; t += 512) {
        const int ge = t & 63, i = t >> 6;
        const float v = (i < 16) ? nsI[idx_i[e0+ge]*16 + i]
                                 : nsJ[idx_j[e0+ge]*16 + (i - 16)];
        sS1T[i*64 + ge] = v;
    }
    // ---- gather V1 (transposed) ----
    for (int t = tid; t < 6144; t += 512) {
        const int ge = t & 63, r = t >> 6;    // r = i*3 + c
        const int i = r / 3, c = r % 3;
        const float v = (i < 16) ? nvI[(idx_i[e0+ge]*16 + i)*3 + c]
                                 : nvJ[(idx_j[e0+ge]*16 + (i - 16))*3 + c];
        sV1T[c*2048 + i*64 + ge] = v;
    }
    __syncthreads();

    const int w  = tid >> 6;                  // wave 0..7
    const int l  = tid & 63;
    const int q  = w & 3;                     // edge quarter
    const int e  = q*16 + (l & 15);           // this lane's A-row edge
    const int ks = l >> 4;                    // k-slice 0..3

    const uint4* Bss = pk;
    const uint4* Bvv = pk + 12288;
    const uint4* Bsv = pk + 18432;
    const uint4* Bvs = pk + 20480;

    // register slices (fixed per lane)
    float s2r[8];
    #pragma unroll
    for (int u = 0; u < 8; ++u) s2r[u] = sS2[e*33 + ks*8 + u];
    float v2r[3][8];
    #pragma unroll
    for (int c = 0; c < 3; ++c)
        #pragma unroll
        for (int u = 0; u < 8; ++u)
            v2r[c][u] = sV2[c*1088 + e*17 + (ks & 1)*8 + u];

    f32x4 acc[3] = {{0,0,0,0},{0,0,0,0},{0,0,0,0}};

    if (w < 4) {
        // ---------------- o_s ----------------
        // G1: A[k=i*32+j] = S1[i] * S2[j]
        for (int i = 0; i < 32; ++i) {
            const float s1 = sS1T[i*64 + e];
            float x[8];
            #pragma unroll
            for (int u = 0; u < 8; ++u) x[u] = s1 * s2r[u];
            F8 ah, al; split8(x, ah, al);
            #pragma unroll
            for (int t = 0; t < 3; ++t) {
                F8 bh, bl;
                ld_b(Bss, ((i*3 + t)*2 + 0)*64 + l, bh);
                ld_b(Bss, ((i*3 + t)*2 + 1)*64 + l, bl);
                acc[t] = mm(ah, bh, acc[t]);
                acc[t] = mm(al, bh, acc[t]);
                acc[t] = mm(ah, bl, acc[t]);
            }
        }
        // G2: A[k=i*16+j] = sum_c V1c[i] * V2c[j]
        for (int n = 0; n < 16; ++n) {
            const int i = 2*n + (ks >> 1);
            const float a0 = sV1T[0*2048 + i*64 + e];
            const float a1 = sV1T[1*2048 + i*64 + e];
            const float a2 = sV1T[2*2048 + i*64 + e];
            float x[8];
            #pragma unroll
            for (int u = 0; u < 8; ++u)
                x[u] = fmaf(a2, v2r[2][u], fmaf(a1, v2r[1][u], a0 * v2r[0][u]));
            F8 ah, al; split8(x, ah, al);
            #pragma unroll
            for (int t = 0; t < 3; ++t) {
                F8 bh, bl;
                ld_b(Bvv, ((n*3 + t)*2 + 0)*64 + l, bh);
                ld_b(Bvv, ((n*3 + t)*2 + 1)*64 + l, bl);
                acc[t] = mm(ah, bh, acc[t]);
                acc[t] = mm(al, bh, acc[t]);
                acc[t] = mm(ah, bl, acc[t]);
            }
        }
    } else {
        // ---------------- o_v ----------------
        // G3: A_c[k=i*16+j] = S1[i] * V2c[j]
        for (int n = 0; n < 16; ++n) {
            const int i = 2*n + (ks >> 1);
            const float s1 = sS1T[i*64 + e];
            F8 bh, bl;
            ld_b(Bsv, (n*2 + 0)*64 + l, bh);
            ld_b(Bsv, (n*2 + 1)*64 + l, bl);
            #pragma unroll
            for (int c = 0; c < 3; ++c) {
                float x[8];
                #pragma unroll
                for (int u = 0; u < 8; ++u) x[u] = s1 * v2r[c][u];
                F8 ah, al; split8(x, ah, al);
                acc[c] = mm(ah, bh, acc[c]);
                acc[c] = mm(al, bh, acc[c]);
                acc[c] = mm(ah, bl, acc[c]);
            }
        }
        // G4: A_c[k=i*32+j] = V1c[i] * S2[j]
        for (int i = 0; i < 32; ++i) {
            F8 bh, bl;
            ld_b(Bvs, (i*2 + 0)*64 + l, bh);
            ld_b(Bvs, (i*2 + 1)*64 + l, bl);
            #pragma unroll
            for (int c = 0; c < 3; ++c) {
                const float v1 = sV1T[c*2048 + i*64 + e];
                float x[8];
                #pragma unroll
                for (int u = 0; u < 8; ++u) x[u] = v1 * s2r[u];
                F8 ah, al; split8(x, ah, al);
                acc[c] = mm(ah, bh, acc[c]);
                acc[c] = mm(al, bh, acc[c]);
                acc[c] = mm(ah, bl, acc[c]);
            }
        }
    }

    __syncthreads();   // all waves done reading LDS sources

    // D layout: col = output = l&15, rows = edges q*16 + ks*4 + r
    if (w < 4) {
        #pragma unroll
        for (int t = 0; t < 3; ++t)
            #pragma unroll
            for (int r = 0; r < 4; ++r)
                sOs[(t*16 + (l & 15))*65 + q*16 + ks*4 + r] = acc[t][r];
    } else {
        #pragma unroll
        for (int c = 0; c < 3; ++c)
            #pragma unroll
            for (int r = 0; r < 4; ++r)
                sOv[((l & 15)*3 + c)*65 + q*16 + ks*4 + r] = acc[c][r];
    }
    __syncthreads();

    // ---- epilogue: silu(o_s[:32]), o_v * sigmoid(o_s[32:48]) — coalesced ----
    for (int t = tid; t < 64*80; t += 512) {
        const int ge = t / 80, f = t % 80;
        float r;
        if (f < 32) {
            const float xv = sOs[f*65 + ge];
            r = xv * fsigmoid(xv);
        } else {
            const int rr = f - 32;                 // rr = o*3 + c
            const int o  = rr / 3;
            r = sOv[rr*65 + ge] * fsigmoid(sOs[(32 + o)*65 + ge]);
        }
        out[(size_t)(e0 + ge)*80 + f] = r;
    }
}

extern "C" void kernel_launch(void* const* d_in, const int* in_sizes, int n_in,
                              void* d_out, int out_size, void* d_ws, size_t ws_size,
                              hipStream_t stream)
{
    const float* edge_sh  = (const float*)d_in[0];
    const float* edge_fea = (const float*)d_in[1];
    const int*   eidx     = (const int*)d_in[2];
    // d_in[3] = batch_edge (unused)
    const float* w1 = (const float*)d_in[4];
    const float* b1 = (const float*)d_in[5];
    const float* w2 = (const float*)d_in[6];
    const float* b2 = (const float*)d_in[7];
    const float* w3 = (const float*)d_in[8];
    const float* b3 = (const float*)d_in[9];
    const float* w_ss = (const float*)d_in[10];
    const float* w_vv = (const float*)d_in[11];
    const float* w_sv = (const float*)d_in[12];
    const float* w_vs = (const float*)d_in[13];
    float* out = (float*)d_out;

    float* ws  = (float*)d_ws;
    float* nsI = ws;                             // [10000][16]
    float* nsJ = ws + 160000;                    // [10000][16]
    float* nvI = ws + 320000;                    // [10000][16][3]
    float* nvJ = ws + 800000;                    // [10000][16][3]
    float* wgtbuf = ws + 1280000;                // [160000][64]
    float* shbuf  = ws + 11520000;               // [160000][4]
    int*   counts  = (int*)(ws + 12160000);      // [10000]
    int*   offsets = counts + NNODES;            // [10001]
    int*   cursor  = offsets + NNODES + 1;       // [10000]
    // packed B-fragments reuse the wgtbuf region (dead after k_reduce);
    // 24576 uint4 = 384 KB, offset 5,120,000 B is 16B-aligned.
    uint4* pkbuf = (uint4*)wgtbuf;

    hipMemsetAsync(counts, 0, NNODES * sizeof(int), stream);
    k_hist<<<625, 256, 0, stream>>>(eidx, counts);
    k_scan<<<1, 256, 0, stream>>>(counts, offsets, cursor);
    k_mlp_store<<<625, 256, 0, stream>>>(edge_sh, edge_fea, eidx,
                                         w1, b1, w2, b2, w3, b3,
                                         cursor, wgtbuf, shbuf);
    k_reduce<<<NNODES/2, 256, 0, stream>>>(offsets, wgtbuf, shbuf,
                                           nsI, nsJ, nvI, nvJ);
    k_pack<<<96, 256, 0, stream>>>(w_ss, w_vv, w_sv, w_vs, pkbuf);
    k_contract<<<2500, 512, 0, stream>>>(edge_fea, eidx, eidx + EDGES,
                                         nsI, nsJ, nvI, nvJ, pkbuf, out);
}

// Round 6
// 416.538 us; speedup vs baseline: 1.6827x; 1.6827x over previous
//
#include <hip/hip_runtime.h>
#include <hip/hip_bf16.h>

#define EDGES 160000
#define NNODES 10000

typedef __attribute__((ext_vector_type(8))) short short8;
typedef __attribute__((ext_vector_type(4))) float f32x4;

__device__ __forceinline__ float fsigmoid(float x) {
    return 1.0f / (1.0f + __expf(-x));
}

union F8 { uint32_t u[4]; short8 s8; };

// packed bf16 pair: low16 = bf16(e0), high16 = bf16(e1), RNE
__device__ __forceinline__ uint32_t pk2(float e0, float e1) {
    uint32_t r;
    asm("v_cvt_pk_bf16_f32 %0, %1, %2" : "=v"(r) : "v"(e0), "v"(e1));
    return r;
}

// Dekker-style split of 8 fp32 into bf16 hi + bf16 lo fragments
__device__ __forceinline__ void split8(const float* x, F8& ah, F8& al) {
    #pragma unroll
    for (int r = 0; r < 4; ++r) {
        const float x0 = x[2*r], x1 = x[2*r+1];
        const uint32_t h = pk2(x0, x1);
        ah.u[r] = h;
        const float f0 = __uint_as_float(h << 16);
        const float f1 = __uint_as_float(h & 0xffff0000u);
        al.u[r] = pk2(x0 - f0, x1 - f1);
    }
}

__device__ __forceinline__ f32x4 mm(const F8& a, const F8& b, f32x4 c) {
    return __builtin_amdgcn_mfma_f32_16x16x32_bf16(a.s8, b.s8, c, 0, 0, 0);
}

__device__ __forceinline__ void ld_b(const uint4* p, int idx, F8& d) {
    const uint4 v = p[idx];
    d.u[0] = v.x; d.u[1] = v.y; d.u[2] = v.z; d.u[3] = v.w;
}

// ---------------------------------------------------------------------------
// Stage A: CSR build
// ---------------------------------------------------------------------------
extern "C" __global__ void __launch_bounds__(256)
k_hist(const int* __restrict__ idx_i, int* __restrict__ counts)
{
    const int e = blockIdx.x * 256 + threadIdx.x;
    if (e < EDGES) atomicAdd(&counts[idx_i[e]], 1);
}

extern "C" __global__ void __launch_bounds__(256)
k_scan(const int* __restrict__ counts, int* __restrict__ offsets,
       int* __restrict__ cursor)
{
    __shared__ int sc[2][256];
    const int t = threadIdx.x;
    const int base = t * 40;
    int loc[40];
    int s = 0;
    #pragma unroll
    for (int k = 0; k < 40; ++k) {
        const int idx = base + k;
        const int c = (idx < NNODES) ? counts[idx] : 0;
        loc[k] = c; s += c;
    }
    sc[0][t] = s;
    __syncthreads();
    int src = 0;
    for (int off = 1; off < 256; off <<= 1) {
        int v = sc[src][t];
        if (t >= off) v += sc[src][t - off];
        sc[src ^ 1][t] = v;
        __syncthreads();
        src ^= 1;
    }
    int run = sc[src][t] - s;          // exclusive prefix
    #pragma unroll
    for (int k = 0; k < 40; ++k) {
        const int idx = base + k;
        if (idx < NNODES) {
            offsets[idx] = run;
            cursor[idx]  = run;
            run += loc[k];
        }
    }
    if (t == 255) offsets[NNODES] = EDGES;
}

// ---------------------------------------------------------------------------
// k_pack_mlp: w1/w2/w3 -> MFMA B-fragment layout, bf16 hi/lo split.
// uint4 index: Lbase + ((kc*4 + nt)*2 + h)*64 + l
//   lane l: n = nt*16 + (l&15), k = kc*32 + (l>>4)*8 + [0..8)
//   word r = pk2(bf16(k=2r), bf16(k=2r+1))
// L1 (K=32) base 0: 512 | L2 (K=64) base 512: 1024 | L3 base 1536: 1024
// ---------------------------------------------------------------------------
extern "C" __global__ void __launch_bounds__(256)
k_pack_mlp(const float* __restrict__ w1, const float* __restrict__ w2,
           const float* __restrict__ w3, uint4* __restrict__ pkw)
{
    const int t = blockIdx.x * 256 + threadIdx.x;     // [0, 2560)
    const float* W; int local;
    if (t < 512)       { W = w1; local = t; }
    else if (t < 1536) { W = w2; local = t - 512; }
    else               { W = w3; local = t - 1536; }

    const int l    = local & 63;
    const int h    = (local >> 6) & 1;
    const int rest = local >> 7;               // kc*4 + nt
    const int nt   = rest & 3;
    const int kc   = rest >> 2;
    const int n    = nt*16 + (l & 15);
    const int kb   = kc*32 + (l >> 4)*8;

    uint32_t out[4];
    #pragma unroll
    for (int r = 0; r < 4; ++r) {
        const float x0 = W[(size_t)(kb + 2*r    )*64 + n];
        const float x1 = W[(size_t)(kb + 2*r + 1)*64 + n];
        const uint32_t hi = pk2(x0, x1);
        if (h == 0) out[r] = hi;
        else {
            const float f0 = __uint_as_float(hi << 16);
            const float f1 = __uint_as_float(hi & 0xffff0000u);
            out[r] = pk2(x0 - f0, x1 - f1);
        }
    }
    pkw[t] = make_uint4(out[0], out[1], out[2], out[3]);
}

// ---------------------------------------------------------------------------
// k_mlp_mfma: MLP (32->64->64->64, silu) on the matrix pipe.
// 256 threads = 4 waves; each wave owns 64 edges (4 m-tiles of 16).
// Weights stream as pre-packed B-fragments (vector loads, L2-cached);
// inter-layer transpose via per-wave LDS [64][68]. Output scattered to
// CSR slots (same wgtbuf/shbuf interface as before).
// ---------------------------------------------------------------------------
extern "C" __global__ void __launch_bounds__(256, 2)
k_mlp_mfma(const float* __restrict__ edge_sh,
           const float* __restrict__ edge_fea,
           const int* __restrict__ idx_i,
           const float* __restrict__ b1, const float* __restrict__ b2,
           const float* __restrict__ b3,
           const uint4* __restrict__ pkw,
           int* __restrict__ cursor,
           float* __restrict__ wgtbuf, float* __restrict__ shbuf)
{
    __shared__ float sAbuf[4][64*68];     // 69632 B: per-wave [64 edges][68]
    __shared__ int   sSlot[256];

    const int tid = threadIdx.x;
    const int w   = tid >> 6, l = tid & 63;
    const int r16 = l & 15, ks = l >> 4;
    const int e0w = blockIdx.x * 256 + w * 64;
    float* A = sAbuf[w];

    // per-edge CSR slot + sh copy (1 edge per lane)
    {
        const int eg = e0w + l;
        const int ni = idx_i[eg];
        const int slot = atomicAdd(&cursor[ni], 1);
        sSlot[tid] = slot;
        *reinterpret_cast<float4*>(shbuf + (size_t)slot * 4) =
            *reinterpret_cast<const float4*>(edge_sh + (size_t)eg * 4);
    }

    f32x4 acc[4][4];

    // ---------------- Layer 1 (K=32) ----------------
    {
        float bias[4];
        #pragma unroll
        for (int nt = 0; nt < 4; ++nt) bias[nt] = b1[nt*16 + r16];
        #pragma unroll
        for (int mt = 0; mt < 4; ++mt)
            #pragma unroll
            for (int nt = 0; nt < 4; ++nt)
                acc[mt][nt] = (f32x4){bias[nt], bias[nt], bias[nt], bias[nt]};

        F8 ah[4], al[4];
        #pragma unroll
        for (int mt = 0; mt < 4; ++mt) {
            const float* src = edge_fea + (size_t)(e0w + mt*16 + r16)*80 + ks*8;
            const float4 v0 = *reinterpret_cast<const float4*>(src);
            const float4 v1 = *reinterpret_cast<const float4*>(src + 4);
            float x[8];
            x[0]=v0.x; x[1]=v0.y; x[2]=v0.z; x[3]=v0.w;
            x[4]=v1.x; x[5]=v1.y; x[6]=v1.z; x[7]=v1.w;
            split8(x, ah[mt], al[mt]);
        }
        #pragma unroll
        for (int nt = 0; nt < 4; ++nt) {
            F8 bh, bl;
            ld_b(pkw, (nt*2 + 0)*64 + l, bh);
            ld_b(pkw, (nt*2 + 1)*64 + l, bl);
            #pragma unroll
            for (int mt = 0; mt < 4; ++mt) {
                acc[mt][nt] = mm(ah[mt], bh, acc[mt][nt]);
                acc[mt][nt] = mm(al[mt], bh, acc[mt][nt]);
                acc[mt][nt] = mm(ah[mt], bl, acc[mt][nt]);
            }
        }
        // silu -> LDS (D: row = mt*16 + ks*4 + r, col = nt*16 + r16)
        #pragma unroll
        for (int mt = 0; mt < 4; ++mt)
            #pragma unroll
            for (int nt = 0; nt < 4; ++nt)
                #pragma unroll
                for (int r = 0; r < 4; ++r) {
                    const float v = acc[mt][nt][r];
                    A[(mt*16 + ks*4 + r)*68 + nt*16 + r16] = v * fsigmoid(v);
                }
    }

    // ---------------- Layers 2 and 3 (K=64) ----------------
    #pragma unroll 1
    for (int layer = 0; layer < 2; ++layer) {
        const uint4* pkl = pkw + 512 + layer*1024;
        const float* bb  = (layer == 0) ? b2 : b3;
        float bias[4];
        #pragma unroll
        for (int nt = 0; nt < 4; ++nt) bias[nt] = bb[nt*16 + r16];
        #pragma unroll
        for (int mt = 0; mt < 4; ++mt)
            #pragma unroll
            for (int nt = 0; nt < 4; ++nt)
                acc[mt][nt] = (f32x4){bias[nt], bias[nt], bias[nt], bias[nt]};

        #pragma unroll
        for (int kc = 0; kc < 2; ++kc) {
            F8 ah[4], al[4];
            #pragma unroll
            for (int mt = 0; mt < 4; ++mt) {
                const float* src = A + (mt*16 + r16)*68 + kc*32 + ks*8;
                const float4 v0 = *reinterpret_cast<const float4*>(src);
                const float4 v1 = *reinterpret_cast<const float4*>(src + 4);
                float x[8];
                x[0]=v0.x; x[1]=v0.y; x[2]=v0.z; x[3]=v0.w;
                x[4]=v1.x; x[5]=v1.y; x[6]=v1.z; x[7]=v1.w;
                split8(x, ah[mt], al[mt]);
            }
            #pragma unroll
            for (int nt = 0; nt < 4; ++nt) {
                F8 bh, bl;
                ld_b(pkl, ((kc*4 + nt)*2 + 0)*64 + l, bh);
                ld_b(pkl, ((kc*4 + nt)*2 + 1)*64 + l, bl);
                #pragma unroll
                for (int mt = 0; mt < 4; ++mt) {
                    acc[mt][nt] = mm(ah[mt], bh, acc[mt][nt]);
                    acc[mt][nt] = mm(al[mt], bh, acc[mt][nt]);
                    acc[mt][nt] = mm(ah[mt], bl, acc[mt][nt]);
                }
            }
        }
        if (layer == 0) {
            #pragma unroll
            for (int mt = 0; mt < 4; ++mt)
                #pragma unroll
                for (int nt = 0; nt < 4; ++nt)
                    #pragma unroll
                    for (int r = 0; r < 4; ++r) {
                        const float v = acc[mt][nt][r];
                        A[(mt*16 + ks*4 + r)*68 + nt*16 + r16] = v * fsigmoid(v);
                    }
        }
    }

    // ---------------- scatter wgt to CSR slots ----------------
    #pragma unroll
    for (int mt = 0; mt < 4; ++mt) {
        int sl[4];
        #pragma unroll
        for (int r = 0; r < 4; ++r)
            sl[r] = sSlot[(tid & ~63) + mt*16 + ks*4 + r];
        #pragma unroll
        for (int nt = 0; nt < 4; ++nt)
            #pragma unroll
            for (int r = 0; r < 4; ++r)
                wgtbuf[(size_t)sl[r]*64 + nt*16 + r16] = acc[mt][nt][r];
    }
}

extern "C" __global__ void __launch_bounds__(256)
k_reduce(const int* __restrict__ offsets,
         const float* __restrict__ wgtbuf, const float* __restrict__ shbuf,
         float* __restrict__ nsI, float* __restrict__ nsJ,
         float* __restrict__ nvI, float* __restrict__ nvJ)
{
    const int tid = threadIdx.x;
    const int n = blockIdx.x * 2 + (tid >> 7);
    const int o = tid & 127;

    int widx, shc;
    float* dst;
    if (o < 16)      { widx = o;            shc = 0;     dst = &nsI[n*16 + o]; }
    else if (o < 64) { const int r = o - 16; const int m = r / 3, c = r - 3*m;
                       widx = 16 + m;       shc = 1 + c; dst = &nvI[(n*16 + m)*3 + c]; }
    else if (o < 80) { const int r = o - 64;
                       widx = 32 + r;       shc = 0;     dst = &nsJ[n*16 + r]; }
    else             { const int r = o - 80; const int m = r / 3, c = r - 3*m;
                       widx = 48 + m;       shc = 1 + c; dst = &nvJ[(n*16 + m)*3 + c]; }

    const int s0 = offsets[n], s1 = offsets[n + 1];
    float acc = 0.0f;
    for (int s = s0; s < s1; ++s)
        acc = fmaf(wgtbuf[(size_t)s*64 + widx], shbuf[(size_t)s*4 + shc], acc);
    *dst = acc;
}

// ---------------------------------------------------------------------------
// k_pack: contraction weights -> MFMA B-fragment layout (unchanged).
// segs: ss[K=1024,t=3]@0  vv[512,3]@12288  sv[512,1]@18432  vs[1024,1]@20480
// ---------------------------------------------------------------------------
extern "C" __global__ void __launch_bounds__(256)
k_pack(const float* __restrict__ w_ss, const float* __restrict__ w_vv,
       const float* __restrict__ w_sv, const float* __restrict__ w_vs,
       uint4* __restrict__ pk)
{
    const int t = blockIdx.x * 256 + threadIdx.x;     // [0, 24576)
    const float INV2  = 0.70710678118654752f;
    const float RS512 = 22.627416997969522f;
    const float C3    = 0.57735026918962576f;

    const float* W; int K; float scale; int local; int tiles;
    if (t < 12288)      { W = w_ss; K = 1024; scale = INV2/32.0f;     local = t;         tiles = 3; }
    else if (t < 18432) { W = w_vv; K = 512;  scale = INV2*C3/RS512;  local = t - 12288; tiles = 3; }
    else if (t < 20480) { W = w_sv; K = 512;  scale = INV2/RS512;     local = t - 18432; tiles = 1; }
    else                { W = w_vs; K = 1024; scale = INV2/32.0f;     local = t - 20480; tiles = 1; }

    const int l    = local & 63;
    const int h    = (local >> 6) & 1;
    const int rest = local >> 7;               // kc*tiles + tile
    const int tile = rest % tiles;
    const int kc   = rest / tiles;
    const int o    = tile*16 + (l & 15);
    const int kb   = kc*32 + (l >> 4)*8;

    const float4* src = reinterpret_cast<const float4*>(W + (size_t)o * K + kb);
    const float4 a = src[0], b = src[1];
    const float v[8] = {a.x, a.y, a.z, a.w, b.x, b.y, b.z, b.w};

    uint32_t out[4];
    #pragma unroll
    for (int r = 0; r < 4; ++r) {
        const float x0 = v[2*r] * scale, x1 = v[2*r+1] * scale;
        const uint32_t hi = pk2(x0, x1);
        if (h == 0) out[r] = hi;
        else {
            const float f0 = __uint_as_float(hi << 16);
            const float f1 = __uint_as_float(hi & 0xffff0000u);
            out[r] = pk2(x0 - f0, x1 - f1);
        }
    }
    pk[t] = make_uint4(out[0], out[1], out[2], out[3]);
}

// ---------------------------------------------------------------------------
// Stage B: MFMA contraction (unchanged from round 4, verified).
// ---------------------------------------------------------------------------
extern "C" __global__ void __launch_bounds__(512)
k_contract(const float* __restrict__ edge_fea,
           const int* __restrict__ idx_i, const int* __restrict__ idx_j,
           const float* __restrict__ nsI, const float* __restrict__ nsJ,
           const float* __restrict__ nvI, const float* __restrict__ nvJ,
           const uint4* __restrict__ pk,
           float* __restrict__ out)
{
    __shared__ float lds[13568];              // 54272 B -> 3 blocks/CU by LDS
    float* sS1T = lds;                        // [32][64]
    float* sS2  = lds + 2048;                 // [64][33] (+1 pad)
    float* sV1T = lds + 4160;                 // [3][32][64]
    float* sV2  = lds + 10304;                // [3][64][17] (+1 pad)
    float* sOs  = lds;                        // [48][65] reuse (epilogue)
    float* sOv  = lds + 4160;                 // [48][65] reuse (epilogue)

    const int tid = threadIdx.x;
    const int e0  = blockIdx.x * 64;

    // ---- gather S2 / V2 from edge_fea ----
    for (int t = tid; t < 64*20; t += 512) {
        const int ge = t & 63, qd = t >> 6;
        const float4 v = *reinterpret_cast<const float4*>(
            edge_fea + (size_t)(e0 + ge) * 80 + qd * 4);
        const float vv4[4] = {v.x, v.y, v.z, v.w};
        #pragma unroll
        for (int u = 0; u < 4; ++u) {
            const int f = qd*4 + u;
            if (f < 32) sS2[ge*33 + f] = vv4[u];
            else {
                const int r = f - 32;               // r = j*3 + c
                sV2[(r % 3)*1088 + ge*17 + r/3] = vv4[u];
            }
        }
    }
    // ---- gather S1 (transposed) ----
    for (int t = tid; t < 2048; t += 512) {
        const int ge = t & 63, i = t >> 6;
        const float v = (i < 16) ? nsI[idx_i[e0+ge]*16 + i]
                                 : nsJ[idx_j[e0+ge]*16 + (i - 16)];
        sS1T[i*64 + ge] = v;
    }
    // ---- gather V1 (transposed) ----
    for (int t = tid; t < 6144; t += 512) {
        const int ge = t & 63, r = t >> 6;    // r = i*3 + c
        const int i = r / 3, c = r % 3;
        const float v = (i < 16) ? nvI[(idx_i[e0+ge]*16 + i)*3 + c]
                                 : nvJ[(idx_j[e0+ge]*16 + (i - 16))*3 + c];
        sV1T[c*2048 + i*64 + ge] = v;
    }
    __syncthreads();

    const int w  = tid >> 6;                  // wave 0..7
    const int l  = tid & 63;
    const int q  = w & 3;                     // edge quarter
    const int e  = q*16 + (l & 15);           // this lane's A-row edge
    const int ks = l >> 4;                    // k-slice 0..3

    const uint4* Bss = pk;
    const uint4* Bvv = pk + 12288;
    const uint4* Bsv = pk + 18432;
    const uint4* Bvs = pk + 20480;

    // register slices (fixed per lane)
    float s2r[8];
    #pragma unroll
    for (int u = 0; u < 8; ++u) s2r[u] = sS2[e*33 + ks*8 + u];
    float v2r[3][8];
    #pragma unroll
    for (int c = 0; c < 3; ++c)
        #pragma unroll
        for (int u = 0; u < 8; ++u)
            v2r[c][u] = sV2[c*1088 + e*17 + (ks & 1)*8 + u];

    f32x4 acc[3] = {{0,0,0,0},{0,0,0,0},{0,0,0,0}};

    if (w < 4) {
        // ---------------- o_s ----------------
        for (int i = 0; i < 32; ++i) {
            const float s1 = sS1T[i*64 + e];
            float x[8];
            #pragma unroll
            for (int u = 0; u < 8; ++u) x[u] = s1 * s2r[u];
            F8 ah, al; split8(x, ah, al);
            #pragma unroll
            for (int t = 0; t < 3; ++t) {
                F8 bh, bl;
                ld_b(Bss, ((i*3 + t)*2 + 0)*64 + l, bh);
                ld_b(Bss, ((i*3 + t)*2 + 1)*64 + l, bl);
                acc[t] = mm(ah, bh, acc[t]);
                acc[t] = mm(al, bh, acc[t]);
                acc[t] = mm(ah, bl, acc[t]);
            }
        }
        for (int n = 0; n < 16; ++n) {
            const int i = 2*n + (ks >> 1);
            const float a0 = sV1T[0*2048 + i*64 + e];
            const float a1 = sV1T[1*2048 + i*64 + e];
            const float a2 = sV1T[2*2048 + i*64 + e];
            float x[8];
            #pragma unroll
            for (int u = 0; u < 8; ++u)
                x[u] = fmaf(a2, v2r[2][u], fmaf(a1, v2r[1][u], a0 * v2r[0][u]));
            F8 ah, al; split8(x, ah, al);
            #pragma unroll
            for (int t = 0; t < 3; ++t) {
                F8 bh, bl;
                ld_b(Bvv, ((n*3 + t)*2 + 0)*64 + l, bh);
                ld_b(Bvv, ((n*3 + t)*2 + 1)*64 + l, bl);
                acc[t] = mm(ah, bh, acc[t]);
                acc[t] = mm(al, bh, acc[t]);
                acc[t] = mm(ah, bl, acc[t]);
            }
        }
    } else {
        // ---------------- o_v ----------------
        for (int n = 0; n < 16; ++n) {
            const int i = 2*n + (ks >> 1);
            const float s1 = sS1T[i*64 + e];
            F8 bh, bl;
            ld_b(Bsv, (n*2 + 0)*64 + l, bh);
            ld_b(Bsv, (n*2 + 1)*64 + l, bl);
            #pragma unroll
            for (int c = 0; c < 3; ++c) {
                float x[8];
                #pragma unroll
                for (int u = 0; u < 8; ++u) x[u] = s1 * v2r[c][u];
                F8 ah, al; split8(x, ah, al);
                acc[c] = mm(ah, bh, acc[c]);
                acc[c] = mm(al, bh, acc[c]);
                acc[c] = mm(ah, bl, acc[c]);
            }
        }
        for (int i = 0; i < 32; ++i) {
            F8 bh, bl;
            ld_b(Bvs, (i*2 + 0)*64 + l, bh);
            ld_b(Bvs, (i*2 + 1)*64 + l, bl);
            #pragma unroll
            for (int c = 0; c < 3; ++c) {
                const float v1 = sV1T[c*2048 + i*64 + e];
                float x[8];
                #pragma unroll
                for (int u = 0; u < 8; ++u) x[u] = v1 * s2r[u];
                F8 ah, al; split8(x, ah, al);
                acc[c] = mm(ah, bh, acc[c]);
                acc[c] = mm(al, bh, acc[c]);
                acc[c] = mm(ah, bl, acc[c]);
            }
        }
    }

    __syncthreads();   // all waves done reading LDS sources

    if (w < 4) {
        #pragma unroll
        for (int t = 0; t < 3; ++t)
            #pragma unroll
            for (int r = 0; r < 4; ++r)
                sOs[(t*16 + (l & 15))*65 + q*16 + ks*4 + r] = acc[t][r];
    } else {
        #pragma unroll
        for (int c = 0; c < 3; ++c)
            #pragma unroll
            for (int r = 0; r < 4; ++r)
                sOv[((l & 15)*3 + c)*65 + q*16 + ks*4 + r] = acc[c][r];
    }
    __syncthreads();

    // ---- epilogue: silu(o_s[:32]), o_v * sigmoid(o_s[32:48]) — coalesced ----
    for (int t = tid; t < 64*80; t += 512) {
        const int ge = t / 80, f = t % 80;
        float r;
        if (f < 32) {
            const float xv = sOs[f*65 + ge];
            r = xv * fsigmoid(xv);
        } else {
            const int rr = f - 32;                 // rr = o*3 + c
            const int o  = rr / 3;
            r = sOv[rr*65 + ge] * fsigmoid(sOs[(32 + o)*65 + ge]);
        }
        out[(size_t)(e0 + ge)*80 + f] = r;
    }
}

extern "C" void kernel_launch(void* const* d_in, const int* in_sizes, int n_in,
                              void* d_out, int out_size, void* d_ws, size_t ws_size,
                              hipStream_t stream)
{
    const float* edge_sh  = (const float*)d_in[0];
    const float* edge_fea = (const float*)d_in[1];
    const int*   eidx     = (const int*)d_in[2];
    // d_in[3] = batch_edge (unused)
    const float* w1 = (const float*)d_in[4];
    const float* b1 = (const float*)d_in[5];
    const float* w2 = (const float*)d_in[6];
    const float* b2 = (const float*)d_in[7];
    const float* w3 = (const float*)d_in[8];
    const float* b3 = (const float*)d_in[9];
    const float* w_ss = (const float*)d_in[10];
    const float* w_vv = (const float*)d_in[11];
    const float* w_sv = (const float*)d_in[12];
    const float* w_vs = (const float*)d_in[13];
    float* out = (float*)d_out;

    float* ws  = (float*)d_ws;
    float* nsI = ws;                             // [10000][16]
    float* nsJ = ws + 160000;                    // [10000][16]
    float* nvI = ws + 320000;                    // [10000][16][3]
    float* nvJ = ws + 800000;                    // [10000][16][3]
    float* wgtbuf = ws + 1280000;                // [160000][64]
    float* shbuf  = ws + 11520000;               // [160000][4]
    int*   counts  = (int*)(ws + 12160000);      // [10000]
    int*   offsets = counts + NNODES;            // [10001]
    int*   cursor  = offsets + NNODES + 1;       // [10000]
    // contraction B-fragments reuse wgtbuf region (dead after k_reduce)
    uint4* pkbuf = (uint4*)wgtbuf;
    // MLP B-fragments (2560 uint4 = 40 KB) parked in d_out — d_out is dead
    // scratch until k_contract fully rewrites every element at the end.
    uint4* pkw = (uint4*)d_out;

    hipMemsetAsync(counts, 0, NNODES * sizeof(int), stream);
    k_hist<<<625, 256, 0, stream>>>(eidx, counts);
    k_scan<<<1, 256, 0, stream>>>(counts, offsets, cursor);
    k_pack_mlp<<<10, 256, 0, stream>>>(w1, w2, w3, pkw);
    k_mlp_mfma<<<625, 256, 0, stream>>>(edge_sh, edge_fea, eidx,
                                        b1, b2, b3, pkw,
                                        cursor, wgtbuf, shbuf);
    k_reduce<<<NNODES/2, 256, 0, stream>>>(offsets, wgtbuf, shbuf,
                                           nsI, nsJ, nvI, nvJ);
    k_pack<<<96, 256, 0, stream>>>(w_ss, w_vv, w_sv, w_vs, pkbuf);
    k_contract<<<2500, 512, 0, stream>>>(edge_fea, eidx, eidx + EDGES,
                                         nsI, nsJ, nvI, nvJ, pkbuf, out);
}